// Round 1
// baseline (841.341 us; speedup 1.0000x reference)
//
#include <hip/hip_runtime.h>

#define N_NODES 50000
#define N_EDGES 800000
#define N_GRAPHS 256
#define D_IN 256
#define D_HID 512
#define MPAD 50048  // 391 * 128, padded row count for GEMM tiles

typedef __attribute__((ext_vector_type(8))) short bf16x8;
typedef __attribute__((ext_vector_type(4))) float f32x4;

static __device__ __forceinline__ unsigned short f2bf(float f) {
  unsigned u = __float_as_uint(f);
  u += 0x7fffu + ((u >> 16) & 1u);  // round-to-nearest-even
  return (unsigned short)(u >> 16);
}

// ---------- small prep kernels ----------

__global__ void k_convert_x(const float* __restrict__ x, unsigned short* __restrict__ xb) {
  int i = blockIdx.x * blockDim.x + threadIdx.x;  // over (N_NODES*D_IN)/4
  if (i >= (N_NODES * D_IN) / 4) return;
  float4 v = ((const float4*)x)[i];
  ushort4 o;
  o.x = f2bf(v.x); o.y = f2bf(v.y); o.z = f2bf(v.z); o.w = f2bf(v.w);
  ((ushort4*)xb)[i] = o;
}

// W [K,512] f32 -> Wt [512,K] bf16
__global__ void k_wt(const float* __restrict__ W, unsigned short* __restrict__ Wt, int K) {
  int i = blockIdx.x * blockDim.x + threadIdx.x;
  if (i >= K * 512) return;
  int k = i >> 9, n = i & 511;
  Wt[n * K + k] = f2bf(W[i]);
}

__global__ void k_deg(const int* __restrict__ edst, int* __restrict__ deg) {
  int i = blockIdx.x * blockDim.x + threadIdx.x;
  if (i < N_EDGES) atomicAdd(&deg[edst[i]], 1);
}

__global__ void k_dinv(const int* __restrict__ deg, float* __restrict__ dinv) {
  int v = blockIdx.x * blockDim.x + threadIdx.x;
  if (v < N_NODES) dinv[v] = rsqrtf((float)(deg[v] + 1));  // +1 self-loop
}

// exclusive scan of deg[N_NODES] -> rowptr[N_NODES+1], single block of 1024
__global__ void k_scan(const int* __restrict__ deg, int* __restrict__ rowptr) {
  __shared__ int wsum[16];
  __shared__ int scarry;
  const int tid = threadIdx.x;
  const int lane = tid & 63, wid = tid >> 6;
  if (tid == 0) scarry = 0;
  __syncthreads();
  for (int base = 0; base < N_NODES; base += 1024) {
    int idx = base + tid;
    int v = (idx < N_NODES) ? deg[idx] : 0;
    int incl = v;
#pragma unroll
    for (int off = 1; off < 64; off <<= 1) {
      int t = __shfl_up(incl, off);
      if (lane >= off) incl += t;
    }
    if (lane == 63) wsum[wid] = incl;
    __syncthreads();
    if (wid == 0 && lane < 16) {
      int wv = wsum[lane];
      int ws = wv;
#pragma unroll
      for (int off = 1; off < 16; off <<= 1) {
        int t = __shfl_up(ws, off);
        if (lane >= off) ws += t;
      }
      wsum[lane] = ws - wv;  // exclusive wave offset
    }
    __syncthreads();
    int wexcl = wsum[wid];
    int c = scarry;
    if (idx < N_NODES) rowptr[idx] = c + wexcl + incl - v;
    __syncthreads();
    if (tid == 1023) scarry = c + wexcl + incl;
    __syncthreads();
  }
  if (threadIdx.x == 0) rowptr[N_NODES] = scarry;
}

__global__ void k_fill(const int* __restrict__ esrc, const int* __restrict__ edst,
                       const int* __restrict__ rowptr, int* __restrict__ cursor,
                       int* __restrict__ csr) {
  int i = blockIdx.x * blockDim.x + threadIdx.x;
  if (i < N_EDGES) {
    int d = edst[i];
    int pos = atomicAdd(&cursor[d], 1);
    csr[rowptr[d] + pos] = esrc[i];
  }
}

__global__ void k_counts(const int* __restrict__ batch, int* __restrict__ counts) {
  int v = blockIdx.x * blockDim.x + threadIdx.x;
  if (v < N_NODES) atomicAdd(&counts[batch[v]], 1);
}

__global__ void k_maxlen(const int* __restrict__ counts, float* __restrict__ ml) {
  int m = 0;
  for (int i = threadIdx.x; i < N_GRAPHS; i += 64) m = max(m, counts[i]);
#pragma unroll
  for (int off = 32; off > 0; off >>= 1) m = max(m, __shfl_xor(m, off));
  if (threadIdx.x == 0) *ml = (float)m;
}

// ---------- GEMM: C[MPAD,512] = A[MPAD,KD](bf16) @ Bt[512,KD](bf16)^T ----------
// 128x128 tile, BK=32, 4 waves of 64x64, mfma_f32_16x16x32_bf16.
// LDS rows padded to 40 elements (80B): fragment ds_read_b128 is 2-way (free).
template <int KD>
__global__ __launch_bounds__(256) void k_gemm(const unsigned short* __restrict__ A,
                                              const unsigned short* __restrict__ Bt,
                                              float* __restrict__ C) {
  constexpr int LDR = 40;
  __shared__ unsigned short As[128 * LDR];
  __shared__ unsigned short Bs[128 * LDR];
  const int tid = threadIdx.x;
  const int m0 = blockIdx.x * 128;
  const int n0 = blockIdx.y * 128;
  const int lane = tid & 63;
  const int wid = tid >> 6;
  const int wm = (wid >> 1) * 64;
  const int wn = (wid & 1) * 64;
  const int fr = lane & 15;  // fragment row (A) / col (B,C)
  const int fq = lane >> 4;  // k-chunk / C row nibble
  const int sr = tid >> 2;   // staging row 0..63
  const int sc = tid & 3;    // staging 16B chunk
  const unsigned short* gA = A + (size_t)(m0 + sr) * KD + sc * 8;
  const unsigned short* gB = Bt + (size_t)(n0 + sr) * KD + sc * 8;
  f32x4 acc[4][4] = {};
  for (int k0 = 0; k0 < KD; k0 += 32) {
    bf16x8 a0 = *(const bf16x8*)(gA + k0);
    bf16x8 a1 = *(const bf16x8*)(gA + (size_t)64 * KD + k0);
    bf16x8 b0 = *(const bf16x8*)(gB + k0);
    bf16x8 b1 = *(const bf16x8*)(gB + (size_t)64 * KD + k0);
    __syncthreads();
    *(bf16x8*)&As[sr * LDR + sc * 8] = a0;
    *(bf16x8*)&As[(sr + 64) * LDR + sc * 8] = a1;
    *(bf16x8*)&Bs[sr * LDR + sc * 8] = b0;
    *(bf16x8*)&Bs[(sr + 64) * LDR + sc * 8] = b1;
    __syncthreads();
    bf16x8 af[4], bfr[4];
#pragma unroll
    for (int i = 0; i < 4; ++i)
      af[i] = *(const bf16x8*)&As[(wm + i * 16 + fr) * LDR + fq * 8];
#pragma unroll
    for (int j = 0; j < 4; ++j)
      bfr[j] = *(const bf16x8*)&Bs[(wn + j * 16 + fr) * LDR + fq * 8];
#pragma unroll
    for (int i = 0; i < 4; ++i)
#pragma unroll
      for (int j = 0; j < 4; ++j)
        acc[i][j] = __builtin_amdgcn_mfma_f32_16x16x32_bf16(af[i], bfr[j], acc[i][j], 0, 0, 0);
  }
#pragma unroll
  for (int i = 0; i < 4; ++i)
#pragma unroll
    for (int j = 0; j < 4; ++j) {
      float* cp = C + (size_t)(m0 + wm + i * 16 + fq * 4) * 512 + (n0 + wn + j * 16 + fr);
#pragma unroll
      for (int jj = 0; jj < 4; ++jj) cp[(size_t)jj * 512] = acc[i][j][jj];
    }
}

// ---------- aggregation ----------
#define MAXE 256
template <int LAYER>
__global__ __launch_bounds__(256) void k_agg(const float* __restrict__ xw,
                                             const float* __restrict__ dinv,
                                             const int* __restrict__ rowptr,
                                             const int* __restrict__ csr,
                                             const float* __restrict__ bias,
                                             const int* __restrict__ batch,
                                             unsigned short* __restrict__ hout,
                                             float* __restrict__ gsums) {
  const int v = blockIdx.x;
  const int tid = threadIdx.x;
  __shared__ int s_src[MAXE];
  __shared__ float s_w[MAXE];
  const float2* xw2 = (const float2*)xw;
  const int e0 = rowptr[v], e1 = rowptr[v + 1];
  const float dv = dinv[v];
  float2 self = xw2[(size_t)v * 256 + tid];
  float a0 = dv * self.x, a1 = dv * self.y;  // self-loop contribution
  for (int eb = e0; eb < e1; eb += MAXE) {
    const int cnt = min(e1 - eb, MAXE);
    __syncthreads();
    if (tid < cnt) {
      int s = csr[eb + tid];
      s_src[tid] = s;
      s_w[tid] = dinv[s];
    }
    __syncthreads();
    for (int i = 0; i < cnt; ++i) {
      const int s = s_src[i];
      const float w = s_w[i];
      float2 t = xw2[(size_t)s * 256 + tid];
      a0 += w * t.x;
      a1 += w * t.y;
    }
  }
  float o0 = dv * a0 + ((const float2*)bias)[tid].x;
  float o1 = dv * a1 + ((const float2*)bias)[tid].y;
  if (LAYER == 1) {
    o0 = fmaxf(o0, 0.f);
    o1 = fmaxf(o1, 0.f);
    ushort2 st;
    st.x = f2bf(o0);
    st.y = f2bf(o1);
    ((ushort2*)hout)[(size_t)v * 256 + tid] = st;
  } else {
    const int g = batch[v];
    atomicAdd(&gsums[g * 512 + 2 * tid], o0);
    atomicAdd(&gsums[g * 512 + 2 * tid + 1], o1);
  }
}

__global__ void k_readout(const float* __restrict__ gsums, const float* __restrict__ ml,
                          float* __restrict__ out) {
  int i = blockIdx.x * blockDim.x + threadIdx.x;
  if (i < N_GRAPHS * D_HID) out[i] = tanhf(gsums[i] / *ml);
}

// ---------- launch ----------

extern "C" void kernel_launch(void* const* d_in, const int* in_sizes, int n_in,
                              void* d_out, int out_size, void* d_ws, size_t ws_size,
                              hipStream_t stream) {
  (void)in_sizes; (void)n_in; (void)out_size; (void)ws_size;
  const float* x = (const float*)d_in[0];
  const float* W1 = (const float*)d_in[1];
  const float* b1 = (const float*)d_in[2];
  const float* W2 = (const float*)d_in[3];
  const float* b2 = (const float*)d_in[4];
  const int* ei = (const int*)d_in[5];
  const int* batch = (const int*)d_in[6];
  const int* esrc = ei;
  const int* edst = ei + N_EDGES;
  float* out = (float*)d_out;

  char* p = (char*)d_ws;
  auto alloc = [&](size_t bytes) {
    char* r = p;
    p += (bytes + 255) & ~(size_t)255;
    return r;
  };
  float* buf_xw = (float*)alloc((size_t)MPAD * 512 * 4);                    // xw1 / xw2
  unsigned short* bfbuf = (unsigned short*)alloc((size_t)MPAD * 512 * 2);   // Xb1 (stride 256) then h1 (stride 512)
  unsigned short* wt = (unsigned short*)alloc((size_t)512 * 512 * 2);
  int* deg = (int*)alloc((size_t)N_NODES * 4);
  int* rowptr = (int*)alloc((size_t)(N_NODES + 4) * 4);
  int* cursor = (int*)alloc((size_t)N_NODES * 4);
  int* csr = (int*)alloc((size_t)N_EDGES * 4);
  int* counts = (int*)alloc(256 * 4);
  float* ml = (float*)alloc(256);
  float* gsums = (float*)alloc((size_t)N_GRAPHS * D_HID * 4);
  float* dinv = (float*)alloc((size_t)N_NODES * 4);

  hipMemsetAsync(deg, 0, (size_t)N_NODES * 4, stream);
  hipMemsetAsync(cursor, 0, (size_t)N_NODES * 4, stream);
  hipMemsetAsync(counts, 0, 256 * 4, stream);
  hipMemsetAsync(gsums, 0, (size_t)N_GRAPHS * D_HID * 4, stream);
  // zero GEMM pad rows (rows N_NODES..MPAD) for both layouts of bfbuf
  hipMemsetAsync((char*)bfbuf + (size_t)N_NODES * D_IN * 2, 0,
                 (size_t)(MPAD - N_NODES) * D_IN * 2, stream);
  hipMemsetAsync((char*)bfbuf + (size_t)N_NODES * D_HID * 2, 0,
                 (size_t)(MPAD - N_NODES) * D_HID * 2, stream);

  k_deg<<<(N_EDGES + 255) / 256, 256, 0, stream>>>(edst, deg);
  k_dinv<<<(N_NODES + 255) / 256, 256, 0, stream>>>(deg, dinv);
  k_scan<<<1, 1024, 0, stream>>>(deg, rowptr);
  k_fill<<<(N_EDGES + 255) / 256, 256, 0, stream>>>(esrc, edst, rowptr, cursor, csr);
  k_counts<<<(N_NODES + 255) / 256, 256, 0, stream>>>(batch, counts);
  k_maxlen<<<1, 64, 0, stream>>>(counts, ml);

  k_convert_x<<<(N_NODES * D_IN / 4 + 255) / 256, 256, 0, stream>>>(x, bfbuf);
  k_wt<<<(256 * 512 + 255) / 256, 256, 0, stream>>>(W1, wt, 256);
  k_gemm<256><<<dim3(MPAD / 128, 4), 256, 0, stream>>>(bfbuf, wt, buf_xw);
  k_agg<1><<<N_NODES, 256, 0, stream>>>(buf_xw, dinv, rowptr, csr, b1, batch, bfbuf, nullptr);
  k_wt<<<(512 * 512 + 255) / 256, 256, 0, stream>>>(W2, wt, 512);
  k_gemm<512><<<dim3(MPAD / 128, 4), 256, 0, stream>>>(bfbuf, wt, buf_xw);
  k_agg<2><<<N_NODES, 256, 0, stream>>>(buf_xw, dinv, rowptr, csr, b2, batch, nullptr, gsums);
  k_readout<<<(N_GRAPHS * D_HID + 255) / 256, 256, 0, stream>>>(gsums, ml, out);
}

// Round 2
// 640.155 us; speedup vs baseline: 1.3143x; 1.3143x over previous
//
#include <hip/hip_runtime.h>

#define N_NODES 50000
#define N_EDGES 800000
#define N_GRAPHS 256
#define D_IN 256
#define D_HID 512
#define MPAD 50048  // 391 * 128, padded row count for GEMM tiles

typedef __attribute__((ext_vector_type(8))) short bf16x8;
typedef __attribute__((ext_vector_type(4))) float f32x4;

static __device__ __forceinline__ unsigned short f2bf(float f) {
  unsigned u = __float_as_uint(f);
  u += 0x7fffu + ((u >> 16) & 1u);  // round-to-nearest-even
  return (unsigned short)(u >> 16);
}
static __device__ __forceinline__ float bf2f(unsigned short h) {
  return __uint_as_float(((unsigned)h) << 16);
}

// ---------- small prep kernels ----------

__global__ void k_convert_x(const float* __restrict__ x, unsigned short* __restrict__ xb) {
  int i = blockIdx.x * blockDim.x + threadIdx.x;  // over (N_NODES*D_IN)/4
  if (i >= (N_NODES * D_IN) / 4) return;
  float4 v = ((const float4*)x)[i];
  ushort4 o;
  o.x = f2bf(v.x); o.y = f2bf(v.y); o.z = f2bf(v.z); o.w = f2bf(v.w);
  ((ushort4*)xb)[i] = o;
}

// W [K,512] f32 -> Wt [512,K] bf16
__global__ void k_wt(const float* __restrict__ W, unsigned short* __restrict__ Wt, int K) {
  int i = blockIdx.x * blockDim.x + threadIdx.x;
  if (i >= K * 512) return;
  int k = i >> 9, n = i & 511;
  Wt[n * K + k] = f2bf(W[i]);
}

__global__ void k_deg(const int* __restrict__ edst, int* __restrict__ deg) {
  int i = blockIdx.x * blockDim.x + threadIdx.x;
  if (i < N_EDGES) atomicAdd(&deg[edst[i]], 1);
}

__global__ void k_dinv(const int* __restrict__ deg, float* __restrict__ dinv) {
  int v = blockIdx.x * blockDim.x + threadIdx.x;
  if (v < N_NODES) dinv[v] = rsqrtf((float)(deg[v] + 1));  // +1 self-loop
}

// exclusive scan of deg[N_NODES] -> rowptr[N_NODES+1], single block of 1024
__global__ void k_scan(const int* __restrict__ deg, int* __restrict__ rowptr) {
  __shared__ int wsum[16];
  __shared__ int scarry;
  const int tid = threadIdx.x;
  const int lane = tid & 63, wid = tid >> 6;
  if (tid == 0) scarry = 0;
  __syncthreads();
  for (int base = 0; base < N_NODES; base += 1024) {
    int idx = base + tid;
    int v = (idx < N_NODES) ? deg[idx] : 0;
    int incl = v;
#pragma unroll
    for (int off = 1; off < 64; off <<= 1) {
      int t = __shfl_up(incl, off);
      if (lane >= off) incl += t;
    }
    if (lane == 63) wsum[wid] = incl;
    __syncthreads();
    if (wid == 0 && lane < 16) {
      int wv = wsum[lane];
      int ws = wv;
#pragma unroll
      for (int off = 1; off < 16; off <<= 1) {
        int t = __shfl_up(ws, off);
        if (lane >= off) ws += t;
      }
      wsum[lane] = ws - wv;  // exclusive wave offset
    }
    __syncthreads();
    int wexcl = wsum[wid];
    int c = scarry;
    if (idx < N_NODES) rowptr[idx] = c + wexcl + incl - v;
    __syncthreads();
    if (tid == 1023) scarry = c + wexcl + incl;
    __syncthreads();
  }
  if (threadIdx.x == 0) rowptr[N_NODES] = scarry;
}

__global__ void k_fill(const int* __restrict__ esrc, const int* __restrict__ edst,
                       const int* __restrict__ rowptr, int* __restrict__ cursor,
                       int* __restrict__ csr) {
  int i = blockIdx.x * blockDim.x + threadIdx.x;
  if (i < N_EDGES) {
    int d = edst[i];
    int pos = atomicAdd(&cursor[d], 1);
    csr[rowptr[d] + pos] = esrc[i];
  }
}

__global__ void k_counts(const int* __restrict__ batch, int* __restrict__ counts) {
  int v = blockIdx.x * blockDim.x + threadIdx.x;
  if (v < N_NODES) atomicAdd(&counts[batch[v]], 1);
}

__global__ void k_maxlen(const int* __restrict__ counts, float* __restrict__ ml) {
  int m = 0;
  for (int i = threadIdx.x; i < N_GRAPHS; i += 64) m = max(m, counts[i]);
#pragma unroll
  for (int off = 32; off > 0; off >>= 1) m = max(m, __shfl_xor(m, off));
  if (threadIdx.x == 0) *ml = (float)m;
}

// ---------- GEMM: C[MPAD,512](bf16) = A[MPAD,KD](bf16) @ Bt[512,KD](bf16)^T ----------
// 128x128 tile, BK=32, 4 waves of 64x64, mfma_f32_16x16x32_bf16.
// LDS rows padded to 40 elements (80B): fragment ds_read_b128 is 2-way (free).
template <int KD>
__global__ __launch_bounds__(256) void k_gemm(const unsigned short* __restrict__ A,
                                              const unsigned short* __restrict__ Bt,
                                              unsigned short* __restrict__ C) {
  constexpr int LDR = 40;
  __shared__ unsigned short As[128 * LDR];
  __shared__ unsigned short Bs[128 * LDR];
  const int tid = threadIdx.x;
  const int m0 = blockIdx.x * 128;
  const int n0 = blockIdx.y * 128;
  const int lane = tid & 63;
  const int wid = tid >> 6;
  const int wm = (wid >> 1) * 64;
  const int wn = (wid & 1) * 64;
  const int fr = lane & 15;  // fragment row (A) / col (B,C)
  const int fq = lane >> 4;  // k-chunk / C row nibble
  const int sr = tid >> 2;   // staging row 0..63
  const int sc = tid & 3;    // staging 16B chunk
  const unsigned short* gA = A + (size_t)(m0 + sr) * KD + sc * 8;
  const unsigned short* gB = Bt + (size_t)(n0 + sr) * KD + sc * 8;
  f32x4 acc[4][4] = {};
  for (int k0 = 0; k0 < KD; k0 += 32) {
    bf16x8 a0 = *(const bf16x8*)(gA + k0);
    bf16x8 a1 = *(const bf16x8*)(gA + (size_t)64 * KD + k0);
    bf16x8 b0 = *(const bf16x8*)(gB + k0);
    bf16x8 b1 = *(const bf16x8*)(gB + (size_t)64 * KD + k0);
    __syncthreads();
    *(bf16x8*)&As[sr * LDR + sc * 8] = a0;
    *(bf16x8*)&As[(sr + 64) * LDR + sc * 8] = a1;
    *(bf16x8*)&Bs[sr * LDR + sc * 8] = b0;
    *(bf16x8*)&Bs[(sr + 64) * LDR + sc * 8] = b1;
    __syncthreads();
    bf16x8 af[4], bfr[4];
#pragma unroll
    for (int i = 0; i < 4; ++i)
      af[i] = *(const bf16x8*)&As[(wm + i * 16 + fr) * LDR + fq * 8];
#pragma unroll
    for (int j = 0; j < 4; ++j)
      bfr[j] = *(const bf16x8*)&Bs[(wn + j * 16 + fr) * LDR + fq * 8];
#pragma unroll
    for (int i = 0; i < 4; ++i)
#pragma unroll
      for (int j = 0; j < 4; ++j)
        acc[i][j] = __builtin_amdgcn_mfma_f32_16x16x32_bf16(af[i], bfr[j], acc[i][j], 0, 0, 0);
  }
#pragma unroll
  for (int i = 0; i < 4; ++i)
#pragma unroll
    for (int j = 0; j < 4; ++j) {
      unsigned short* cp = C + (size_t)(m0 + wm + i * 16 + fq * 4) * 512 + (n0 + wn + j * 16 + fr);
#pragma unroll
      for (int jj = 0; jj < 4; ++jj) cp[(size_t)jj * 512] = f2bf(acc[i][j][jj]);
    }
}

// ---------- aggregation ----------
// One node per block; 4 waves split the edge list; each lane reads a 16B bf16x8
// chunk so one wave covers a full 1KB row per load instruction. f32 accum.
#define MAXE 256
template <int LAYER>
__global__ __launch_bounds__(256) void k_agg(const unsigned short* __restrict__ xw,
                                             const float* __restrict__ dinv,
                                             const int* __restrict__ rowptr,
                                             const int* __restrict__ csr,
                                             const float* __restrict__ bias,
                                             const int* __restrict__ batch,
                                             unsigned short* __restrict__ hout,
                                             float* __restrict__ gsums) {
  const int v = blockIdx.x;
  const int tid = threadIdx.x;
  const int lane = tid & 63, wid = tid >> 6;
  __shared__ int s_src[MAXE];
  __shared__ float s_w[MAXE];
  __shared__ float s_red[4][520];  // 520 stride: row offset % 32 banks = 8 (no conflict pattern)
  const int e0 = rowptr[v], e1 = rowptr[v + 1];
  float acc[8] = {};
  for (int eb = e0; eb < e1; eb += MAXE) {
    const int cnt = min(e1 - eb, MAXE);
    __syncthreads();
    if (tid < cnt) {
      int s = csr[eb + tid];
      s_src[tid] = s;
      s_w[tid] = dinv[s];
    }
    __syncthreads();
    for (int i = wid; i < cnt; i += 4) {
      const int s = s_src[i];
      const float w = s_w[i];
      bf16x8 t = *(const bf16x8*)(xw + (size_t)s * 512 + lane * 8);
#pragma unroll
      for (int j = 0; j < 8; ++j) acc[j] += w * bf2f((unsigned short)t[j]);
    }
  }
#pragma unroll
  for (int j = 0; j < 8; ++j) s_red[wid][lane * 8 + j] = acc[j];
  __syncthreads();
  // thread t owns columns 2t, 2t+1
  const float dv = dinv[v];
  const int c = 2 * tid;
  float o0 = s_red[0][c] + s_red[1][c] + s_red[2][c] + s_red[3][c];
  float o1 = s_red[0][c + 1] + s_red[1][c + 1] + s_red[2][c + 1] + s_red[3][c + 1];
  ushort2 sv = ((const ushort2*)xw)[(size_t)v * 256 + tid];  // self row
  float2 bb = ((const float2*)bias)[tid];
  o0 = dv * (o0 + dv * bf2f(sv.x)) + bb.x;
  o1 = dv * (o1 + dv * bf2f(sv.y)) + bb.y;
  if (LAYER == 1) {
    o0 = fmaxf(o0, 0.f);
    o1 = fmaxf(o1, 0.f);
    ushort2 st;
    st.x = f2bf(o0);
    st.y = f2bf(o1);
    ((ushort2*)hout)[(size_t)v * 256 + tid] = st;
  } else {
    const int g = batch[v];
    atomicAdd(&gsums[g * 512 + c], o0);
    atomicAdd(&gsums[g * 512 + c + 1], o1);
  }
}

__global__ void k_readout(const float* __restrict__ gsums, const float* __restrict__ ml,
                          float* __restrict__ out) {
  int i = blockIdx.x * blockDim.x + threadIdx.x;
  if (i < N_GRAPHS * D_HID) out[i] = tanhf(gsums[i] / *ml);
}

// ---------- launch ----------

extern "C" void kernel_launch(void* const* d_in, const int* in_sizes, int n_in,
                              void* d_out, int out_size, void* d_ws, size_t ws_size,
                              hipStream_t stream) {
  (void)in_sizes; (void)n_in; (void)out_size; (void)ws_size;
  const float* x = (const float*)d_in[0];
  const float* W1 = (const float*)d_in[1];
  const float* b1 = (const float*)d_in[2];
  const float* W2 = (const float*)d_in[3];
  const float* b2 = (const float*)d_in[4];
  const int* ei = (const int*)d_in[5];
  const int* batch = (const int*)d_in[6];
  const int* esrc = ei;
  const int* edst = ei + N_EDGES;
  float* out = (float*)d_out;

  char* p = (char*)d_ws;
  auto alloc = [&](size_t bytes) {
    char* r = p;
    p += (bytes + 255) & ~(size_t)255;
    return r;
  };
  unsigned short* xb = (unsigned short*)alloc((size_t)MPAD * D_IN * 2);    // bf16 X
  unsigned short* h1 = (unsigned short*)alloc((size_t)MPAD * D_HID * 2);   // bf16 hidden
  unsigned short* xwb = (unsigned short*)alloc((size_t)MPAD * D_HID * 2);  // bf16 XW (both layers)
  unsigned short* wt = (unsigned short*)alloc((size_t)512 * 512 * 2);
  int* deg = (int*)alloc((size_t)N_NODES * 4);
  int* rowptr = (int*)alloc((size_t)(N_NODES + 4) * 4);
  int* cursor = (int*)alloc((size_t)N_NODES * 4);
  int* csr = (int*)alloc((size_t)N_EDGES * 4);
  int* counts = (int*)alloc(256 * 4);
  float* ml = (float*)alloc(256);
  float* gsums = (float*)alloc((size_t)N_GRAPHS * D_HID * 4);
  float* dinv = (float*)alloc((size_t)N_NODES * 4);

  hipMemsetAsync(deg, 0, (size_t)N_NODES * 4, stream);
  hipMemsetAsync(cursor, 0, (size_t)N_NODES * 4, stream);
  hipMemsetAsync(counts, 0, 256 * 4, stream);
  hipMemsetAsync(gsums, 0, (size_t)N_GRAPHS * D_HID * 4, stream);
  // zero GEMM pad rows (rows N_NODES..MPAD) of the two GEMM input buffers
  hipMemsetAsync((char*)xb + (size_t)N_NODES * D_IN * 2, 0,
                 (size_t)(MPAD - N_NODES) * D_IN * 2, stream);
  hipMemsetAsync((char*)h1 + (size_t)N_NODES * D_HID * 2, 0,
                 (size_t)(MPAD - N_NODES) * D_HID * 2, stream);

  k_deg<<<(N_EDGES + 255) / 256, 256, 0, stream>>>(edst, deg);
  k_dinv<<<(N_NODES + 255) / 256, 256, 0, stream>>>(deg, dinv);
  k_scan<<<1, 1024, 0, stream>>>(deg, rowptr);
  k_fill<<<(N_EDGES + 255) / 256, 256, 0, stream>>>(esrc, edst, rowptr, cursor, csr);
  k_counts<<<(N_NODES + 255) / 256, 256, 0, stream>>>(batch, counts);
  k_maxlen<<<1, 64, 0, stream>>>(counts, ml);

  k_convert_x<<<(N_NODES * D_IN / 4 + 255) / 256, 256, 0, stream>>>(x, xb);
  k_wt<<<(256 * 512 + 255) / 256, 256, 0, stream>>>(W1, wt, 256);
  k_gemm<256><<<dim3(MPAD / 128, 4), 256, 0, stream>>>(xb, wt, xwb);
  k_agg<1><<<N_NODES, 256, 0, stream>>>(xwb, dinv, rowptr, csr, b1, batch, h1, nullptr);
  k_wt<<<(512 * 512 + 255) / 256, 256, 0, stream>>>(W2, wt, 512);
  k_gemm<512><<<dim3(MPAD / 128, 4), 256, 0, stream>>>(h1, wt, xwb);
  k_agg<2><<<N_NODES, 256, 0, stream>>>(xwb, dinv, rowptr, csr, b2, batch, nullptr, gsums);
  k_readout<<<(N_GRAPHS * D_HID + 255) / 256, 256, 0, stream>>>(gsums, ml, out);
}

// Round 3
// 599.217 us; speedup vs baseline: 1.4041x; 1.0683x over previous
//
#include <hip/hip_runtime.h>

#define N_NODES 50000
#define N_EDGES 800000
#define N_GRAPHS 256
#define D_IN 256
#define D_HID 512
#define MPAD 50048  // 391 * 128, padded row count for GEMM tiles

typedef __attribute__((ext_vector_type(8))) short bf16x8;
typedef __attribute__((ext_vector_type(4))) short bf16x4;
typedef __attribute__((ext_vector_type(4))) float f32x4;

static __device__ __forceinline__ unsigned short f2bf(float f) {
  unsigned u = __float_as_uint(f);
  u += 0x7fffu + ((u >> 16) & 1u);  // round-to-nearest-even
  return (unsigned short)(u >> 16);
}
static __device__ __forceinline__ float bf2f(unsigned short h) {
  return __uint_as_float(((unsigned)h) << 16);
}

// ---------- small prep kernels ----------

__global__ void k_convert_x(const float* __restrict__ x, unsigned short* __restrict__ xb) {
  int i = blockIdx.x * blockDim.x + threadIdx.x;  // over (N_NODES*D_IN)/4
  if (i >= (N_NODES * D_IN) / 4) return;
  float4 v = ((const float4*)x)[i];
  ushort4 o;
  o.x = f2bf(v.x); o.y = f2bf(v.y); o.z = f2bf(v.z); o.w = f2bf(v.w);
  ((ushort4*)xb)[i] = o;
}

// W [K,512] f32 -> Wt [512,K] bf16
__global__ void k_wt(const float* __restrict__ W, unsigned short* __restrict__ Wt, int K) {
  int i = blockIdx.x * blockDim.x + threadIdx.x;
  if (i >= K * 512) return;
  int k = i >> 9, n = i & 511;
  Wt[n * K + k] = f2bf(W[i]);
}

__global__ void k_deg(const int* __restrict__ edst, int* __restrict__ deg) {
  int i = blockIdx.x * blockDim.x + threadIdx.x;
  if (i < N_EDGES) atomicAdd(&deg[edst[i]], 1);
}

__global__ void k_dinv(const int* __restrict__ deg, float* __restrict__ dinv) {
  int v = blockIdx.x * blockDim.x + threadIdx.x;
  if (v < N_NODES) dinv[v] = rsqrtf((float)(deg[v] + 1));  // +1 self-loop
}

// exclusive scan of deg[N_NODES] -> rowptr[N_NODES+1], single block of 1024
__global__ void k_scan(const int* __restrict__ deg, int* __restrict__ rowptr) {
  __shared__ int wsum[16];
  __shared__ int scarry;
  const int tid = threadIdx.x;
  const int lane = tid & 63, wid = tid >> 6;
  if (tid == 0) scarry = 0;
  __syncthreads();
  for (int base = 0; base < N_NODES; base += 1024) {
    int idx = base + tid;
    int v = (idx < N_NODES) ? deg[idx] : 0;
    int incl = v;
#pragma unroll
    for (int off = 1; off < 64; off <<= 1) {
      int t = __shfl_up(incl, off);
      if (lane >= off) incl += t;
    }
    if (lane == 63) wsum[wid] = incl;
    __syncthreads();
    if (wid == 0 && lane < 16) {
      int wv = wsum[lane];
      int ws = wv;
#pragma unroll
      for (int off = 1; off < 16; off <<= 1) {
        int t = __shfl_up(ws, off);
        if (lane >= off) ws += t;
      }
      wsum[lane] = ws - wv;  // exclusive wave offset
    }
    __syncthreads();
    int wexcl = wsum[wid];
    int c = scarry;
    if (idx < N_NODES) rowptr[idx] = c + wexcl + incl - v;
    __syncthreads();
    if (tid == 1023) scarry = c + wexcl + incl;
    __syncthreads();
  }
  if (threadIdx.x == 0) rowptr[N_NODES] = scarry;
}

__global__ void k_fill(const int* __restrict__ esrc, const int* __restrict__ edst,
                       const int* __restrict__ rowptr, int* __restrict__ cursor,
                       int* __restrict__ csr) {
  int i = blockIdx.x * blockDim.x + threadIdx.x;
  if (i < N_EDGES) {
    int d = edst[i];
    int pos = atomicAdd(&cursor[d], 1);
    csr[rowptr[d] + pos] = esrc[i];
  }
}

__global__ void k_counts(const int* __restrict__ batch, int* __restrict__ counts) {
  int v = blockIdx.x * blockDim.x + threadIdx.x;
  if (v < N_NODES) atomicAdd(&counts[batch[v]], 1);
}

__global__ void k_maxlen(const int* __restrict__ counts, float* __restrict__ ml) {
  int m = 0;
  for (int i = threadIdx.x; i < N_GRAPHS; i += 64) m = max(m, counts[i]);
#pragma unroll
  for (int off = 32; off > 0; off >>= 1) m = max(m, __shfl_xor(m, off));
  if (threadIdx.x == 0) *ml = (float)m;
}

// ---------- GEMM: C[MPAD,512](bf16) = A[MPAD,KD](bf16) @ Bt[512,KD](bf16)^T ----------
// 128x128 tile, BK=32, 4 waves of 64x64, mfma_f32_16x16x32_bf16.
// EPI=1: fuse bias + relu into the epilogue.
template <int KD, int EPI>
__global__ __launch_bounds__(256) void k_gemm(const unsigned short* __restrict__ A,
                                              const unsigned short* __restrict__ Bt,
                                              const float* __restrict__ bias,
                                              unsigned short* __restrict__ C) {
  constexpr int LDR = 40;
  __shared__ unsigned short As[128 * LDR];
  __shared__ unsigned short Bs[128 * LDR];
  const int tid = threadIdx.x;
  const int m0 = blockIdx.x * 128;
  const int n0 = blockIdx.y * 128;
  const int lane = tid & 63;
  const int wid = tid >> 6;
  const int wm = (wid >> 1) * 64;
  const int wn = (wid & 1) * 64;
  const int fr = lane & 15;  // fragment row (A) / col (B,C)
  const int fq = lane >> 4;  // k-chunk / C row nibble
  const int sr = tid >> 2;   // staging row 0..63
  const int sc = tid & 3;    // staging 16B chunk
  const unsigned short* gA = A + (size_t)(m0 + sr) * KD + sc * 8;
  const unsigned short* gB = Bt + (size_t)(n0 + sr) * KD + sc * 8;
  f32x4 acc[4][4] = {};
  for (int k0 = 0; k0 < KD; k0 += 32) {
    bf16x8 a0 = *(const bf16x8*)(gA + k0);
    bf16x8 a1 = *(const bf16x8*)(gA + (size_t)64 * KD + k0);
    bf16x8 b0 = *(const bf16x8*)(gB + k0);
    bf16x8 b1 = *(const bf16x8*)(gB + (size_t)64 * KD + k0);
    __syncthreads();
    *(bf16x8*)&As[sr * LDR + sc * 8] = a0;
    *(bf16x8*)&As[(sr + 64) * LDR + sc * 8] = a1;
    *(bf16x8*)&Bs[sr * LDR + sc * 8] = b0;
    *(bf16x8*)&Bs[(sr + 64) * LDR + sc * 8] = b1;
    __syncthreads();
    bf16x8 af[4], bfr[4];
#pragma unroll
    for (int i = 0; i < 4; ++i)
      af[i] = *(const bf16x8*)&As[(wm + i * 16 + fr) * LDR + fq * 8];
#pragma unroll
    for (int j = 0; j < 4; ++j)
      bfr[j] = *(const bf16x8*)&Bs[(wn + j * 16 + fr) * LDR + fq * 8];
#pragma unroll
    for (int i = 0; i < 4; ++i)
#pragma unroll
      for (int j = 0; j < 4; ++j)
        acc[i][j] = __builtin_amdgcn_mfma_f32_16x16x32_bf16(af[i], bfr[j], acc[i][j], 0, 0, 0);
  }
  float bcol[4];
#pragma unroll
  for (int j = 0; j < 4; ++j) bcol[j] = EPI ? bias[n0 + wn + j * 16 + fr] : 0.f;
#pragma unroll
  for (int i = 0; i < 4; ++i)
#pragma unroll
    for (int j = 0; j < 4; ++j) {
      unsigned short* cp = C + (size_t)(m0 + wm + i * 16 + fq * 4) * 512 + (n0 + wn + j * 16 + fr);
#pragma unroll
      for (int jj = 0; jj < 4; ++jj) {
        float vv = acc[i][j][jj];
        if (EPI) vv = fmaxf(vv + bcol[j], 0.f);
        cp[(size_t)jj * 512] = f2bf(vv);
      }
    }
}

// ---------- aggregation ----------
// One node per block; 4 waves split the edge list, edge-pair unrolled (2 row
// loads in flight per wave). f32 accum, conflict-free LDS cross-wave reduce.
// MODE 0: out = dinv*(sum + dinv*self), store bf16 (layer-1 pre-aggregation)
// MODE 2: out = dinv*(sum + dinv*self) + bias, atomicAdd into graph sums
#define MAXE 256
template <int D, int MODE>
__global__ __launch_bounds__(256) void k_agg(const unsigned short* __restrict__ xw,
                                             const float* __restrict__ dinv,
                                             const int* __restrict__ rowptr,
                                             const int* __restrict__ csr,
                                             const float* __restrict__ bias,
                                             const int* __restrict__ batch,
                                             unsigned short* __restrict__ hout,
                                             float* __restrict__ gsums) {
  constexpr int VEC = D / 64;     // elems per lane (4 or 8)
  constexpr int SP = VEC + 1;     // padded stride: gcd(SP,32)=1 -> conflict-free
  const int v = blockIdx.x;
  const int tid = threadIdx.x;
  const int lane = tid & 63, wid = tid >> 6;
  __shared__ int s_src[MAXE];
  __shared__ float s_w[MAXE];
  __shared__ float s_red[4][64 * SP];
  const int e0 = rowptr[v], e1 = rowptr[v + 1];
  float acc[VEC] = {};
  const unsigned short* rowbase = xw + lane * VEC;
  for (int eb = e0; eb < e1; eb += MAXE) {
    const int cnt = min(e1 - eb, MAXE);
    __syncthreads();
    if (tid < cnt) {
      int s = csr[eb + tid];
      s_src[tid] = s;
      s_w[tid] = dinv[s];
    }
    __syncthreads();
    int i = wid;
    for (; i + 4 < cnt; i += 8) {
      const int s0 = s_src[i], s1 = s_src[i + 4];
      const float w0 = s_w[i], w1 = s_w[i + 4];
      if (VEC == 8) {
        bf16x8 t0 = *(const bf16x8*)(rowbase + (size_t)s0 * D);
        bf16x8 t1 = *(const bf16x8*)(rowbase + (size_t)s1 * D);
#pragma unroll
        for (int j = 0; j < VEC; ++j) acc[j] += w0 * bf2f((unsigned short)t0[j]);
#pragma unroll
        for (int j = 0; j < VEC; ++j) acc[j] += w1 * bf2f((unsigned short)t1[j]);
      } else {
        bf16x4 t0 = *(const bf16x4*)(rowbase + (size_t)s0 * D);
        bf16x4 t1 = *(const bf16x4*)(rowbase + (size_t)s1 * D);
#pragma unroll
        for (int j = 0; j < VEC; ++j) acc[j] += w0 * bf2f((unsigned short)t0[j]);
#pragma unroll
        for (int j = 0; j < VEC; ++j) acc[j] += w1 * bf2f((unsigned short)t1[j]);
      }
    }
    if (i < cnt) {
      const int s0 = s_src[i];
      const float w0 = s_w[i];
      if (VEC == 8) {
        bf16x8 t0 = *(const bf16x8*)(rowbase + (size_t)s0 * D);
#pragma unroll
        for (int j = 0; j < VEC; ++j) acc[j] += w0 * bf2f((unsigned short)t0[j]);
      } else {
        bf16x4 t0 = *(const bf16x4*)(rowbase + (size_t)s0 * D);
#pragma unroll
        for (int j = 0; j < VEC; ++j) acc[j] += w0 * bf2f((unsigned short)t0[j]);
      }
    }
  }
#pragma unroll
  for (int j = 0; j < VEC; ++j) s_red[wid][lane * SP + j] = acc[j];
  __syncthreads();
  const float dv = dinv[v];
  if (MODE == 0) {
    // thread t owns dim t (D==256)
    const int c = tid;
    const int co = (c / VEC) * SP + (c % VEC);
    float o = s_red[0][co] + s_red[1][co] + s_red[2][co] + s_red[3][co];
    float self = bf2f(xw[(size_t)v * D + c]);
    hout[(size_t)v * D + c] = f2bf(dv * (o + dv * self));
  } else {
    // thread t owns dims 2t, 2t+1 (D==512)
    const int c = 2 * tid;
    const int co0 = (c / VEC) * SP + (c % VEC);
    const int co1 = ((c + 1) / VEC) * SP + ((c + 1) % VEC);
    float o0 = s_red[0][co0] + s_red[1][co0] + s_red[2][co0] + s_red[3][co0];
    float o1 = s_red[0][co1] + s_red[1][co1] + s_red[2][co1] + s_red[3][co1];
    ushort2 sv = ((const ushort2*)xw)[(size_t)v * (D / 2) + tid];
    float2 bb = ((const float2*)bias)[tid];
    o0 = dv * (o0 + dv * bf2f(sv.x)) + bb.x;
    o1 = dv * (o1 + dv * bf2f(sv.y)) + bb.y;
    const int g = batch[v];
    atomicAdd(&gsums[g * 512 + c], o0);
    atomicAdd(&gsums[g * 512 + c + 1], o1);
  }
}

__global__ void k_readout(const float* __restrict__ gsums, const float* __restrict__ ml,
                          float* __restrict__ out) {
  int i = blockIdx.x * blockDim.x + threadIdx.x;
  if (i < N_GRAPHS * D_HID) out[i] = tanhf(gsums[i] / *ml);
}

// ---------- launch ----------

extern "C" void kernel_launch(void* const* d_in, const int* in_sizes, int n_in,
                              void* d_out, int out_size, void* d_ws, size_t ws_size,
                              hipStream_t stream) {
  (void)in_sizes; (void)n_in; (void)out_size; (void)ws_size;
  const float* x = (const float*)d_in[0];
  const float* W1 = (const float*)d_in[1];
  const float* b1 = (const float*)d_in[2];
  const float* W2 = (const float*)d_in[3];
  const float* b2 = (const float*)d_in[4];
  const int* ei = (const int*)d_in[5];
  const int* batch = (const int*)d_in[6];
  const int* esrc = ei;
  const int* edst = ei + N_EDGES;
  float* out = (float*)d_out;

  char* p = (char*)d_ws;
  auto alloc = [&](size_t bytes) {
    char* r = p;
    p += (bytes + 255) & ~(size_t)255;
    return r;
  };
  unsigned short* xb = (unsigned short*)alloc((size_t)N_NODES * D_IN * 2);  // bf16 X
  unsigned short* ag1 = (unsigned short*)alloc((size_t)MPAD * D_IN * 2);    // bf16 N(A)X
  unsigned short* h1 = (unsigned short*)alloc((size_t)MPAD * D_HID * 2);    // bf16 hidden
  unsigned short* xw2 = (unsigned short*)alloc((size_t)MPAD * D_HID * 2);   // bf16 h1@W2
  unsigned short* wt = (unsigned short*)alloc((size_t)512 * 512 * 2);
  int* deg = (int*)alloc((size_t)N_NODES * 4);
  int* rowptr = (int*)alloc((size_t)(N_NODES + 4) * 4);
  int* cursor = (int*)alloc((size_t)N_NODES * 4);
  int* csr = (int*)alloc((size_t)N_EDGES * 4);
  int* counts = (int*)alloc(256 * 4);
  float* ml = (float*)alloc(256);
  float* gsums = (float*)alloc((size_t)N_GRAPHS * D_HID * 4);
  float* dinv = (float*)alloc((size_t)N_NODES * 4);

  hipMemsetAsync(deg, 0, (size_t)N_NODES * 4, stream);
  hipMemsetAsync(cursor, 0, (size_t)N_NODES * 4, stream);
  hipMemsetAsync(counts, 0, 256 * 4, stream);
  hipMemsetAsync(gsums, 0, (size_t)N_GRAPHS * D_HID * 4, stream);
  // zero GEMM pad rows (rows N_NODES..MPAD) of the two GEMM input buffers
  hipMemsetAsync((char*)ag1 + (size_t)N_NODES * D_IN * 2, 0,
                 (size_t)(MPAD - N_NODES) * D_IN * 2, stream);
  hipMemsetAsync((char*)h1 + (size_t)N_NODES * D_HID * 2, 0,
                 (size_t)(MPAD - N_NODES) * D_HID * 2, stream);

  k_deg<<<(N_EDGES + 255) / 256, 256, 0, stream>>>(edst, deg);
  k_dinv<<<(N_NODES + 255) / 256, 256, 0, stream>>>(deg, dinv);
  k_scan<<<1, 1024, 0, stream>>>(deg, rowptr);
  k_fill<<<(N_EDGES + 255) / 256, 256, 0, stream>>>(esrc, edst, rowptr, cursor, csr);
  k_counts<<<(N_NODES + 255) / 256, 256, 0, stream>>>(batch, counts);
  k_maxlen<<<1, 64, 0, stream>>>(counts, ml);

  k_convert_x<<<(N_NODES * D_IN / 4 + 255) / 256, 256, 0, stream>>>(x, xb);
  // layer 1: aggregate X (256 dims) first, then GEMM with fused bias+relu
  k_agg<256, 0><<<N_NODES, 256, 0, stream>>>(xb, dinv, rowptr, csr, nullptr, nullptr, ag1, nullptr);
  k_wt<<<(256 * 512 + 255) / 256, 256, 0, stream>>>(W1, wt, 256);
  k_gemm<256, 1><<<dim3(MPAD / 128, 4), 256, 0, stream>>>(ag1, wt, b1, h1);
  // layer 2: GEMM then aggregate (512 dims)
  k_wt<<<(512 * 512 + 255) / 256, 256, 0, stream>>>(W2, wt, 512);
  k_gemm<512, 0><<<dim3(MPAD / 128, 4), 256, 0, stream>>>(h1, wt, nullptr, xw2);
  k_agg<512, 2><<<N_NODES, 256, 0, stream>>>(xw2, dinv, rowptr, csr, b2, batch, nullptr, gsums);
  k_readout<<<(N_GRAPHS * D_HID + 255) / 256, 256, 0, stream>>>(gsums, ml, out);
}

// Round 4
// 504.044 us; speedup vs baseline: 1.6692x; 1.1888x over previous
//
#include <hip/hip_runtime.h>

#define N_NODES 50000
#define N_EDGES 800000
#define N_GRAPHS 256
#define D_IN 256
#define D_HID 512
#define MPAD 50048  // 391 * 128, padded row/K count
#define NKS 32      // K-splits for the z-GEMM
#define KSPAN 1568  // 49 * 32 k per split; 32*1568 >= 50048

typedef __attribute__((ext_vector_type(8))) short bf16x8;
typedef __attribute__((ext_vector_type(4))) short bf16x4;
typedef __attribute__((ext_vector_type(4))) float f32x4;

static __device__ __forceinline__ unsigned short f2bf(float f) {
  unsigned u = __float_as_uint(f);
  u += 0x7fffu + ((u >> 16) & 1u);  // round-to-nearest-even
  return (unsigned short)(u >> 16);
}
static __device__ __forceinline__ float bf2f(unsigned short h) {
  return __uint_as_float(((unsigned)h) << 16);
}

// ---------- small prep kernels ----------

__global__ void k_convert_x(const float* __restrict__ x, unsigned short* __restrict__ xb) {
  int i = blockIdx.x * blockDim.x + threadIdx.x;  // over (N_NODES*D_IN)/4
  if (i >= (N_NODES * D_IN) / 4) return;
  float4 v = ((const float4*)x)[i];
  ushort4 o;
  o.x = f2bf(v.x); o.y = f2bf(v.y); o.z = f2bf(v.z); o.w = f2bf(v.w);
  ((ushort4*)xb)[i] = o;
}

// W1 [256,512] f32 -> Wt [512,256] bf16
__global__ void k_wt(const float* __restrict__ W, unsigned short* __restrict__ Wt) {
  int i = blockIdx.x * blockDim.x + threadIdx.x;
  if (i >= 256 * 512) return;
  int k = i >> 9, n = i & 511;
  Wt[n * 256 + k] = f2bf(W[i]);
}

__global__ void k_deg(const int* __restrict__ edst, int* __restrict__ deg) {
  int i = blockIdx.x * blockDim.x + threadIdx.x;
  if (i < N_EDGES) atomicAdd(&deg[edst[i]], 1);
}

__global__ void k_dinv(const int* __restrict__ deg, float* __restrict__ dinv) {
  int v = blockIdx.x * blockDim.x + threadIdx.x;
  if (v < N_NODES) dinv[v] = rsqrtf((float)(deg[v] + 1));  // +1 self-loop
}

// exclusive scan of deg[N_NODES] -> rowptr[N_NODES+1], single block of 1024
__global__ void k_scan(const int* __restrict__ deg, int* __restrict__ rowptr) {
  __shared__ int wsum[16];
  __shared__ int scarry;
  const int tid = threadIdx.x;
  const int lane = tid & 63, wid = tid >> 6;
  if (tid == 0) scarry = 0;
  __syncthreads();
  for (int base = 0; base < N_NODES; base += 1024) {
    int idx = base + tid;
    int v = (idx < N_NODES) ? deg[idx] : 0;
    int incl = v;
#pragma unroll
    for (int off = 1; off < 64; off <<= 1) {
      int t = __shfl_up(incl, off);
      if (lane >= off) incl += t;
    }
    if (lane == 63) wsum[wid] = incl;
    __syncthreads();
    if (wid == 0 && lane < 16) {
      int wv = wsum[lane];
      int ws = wv;
#pragma unroll
      for (int off = 1; off < 16; off <<= 1) {
        int t = __shfl_up(ws, off);
        if (lane >= off) ws += t;
      }
      wsum[lane] = ws - wv;  // exclusive wave offset
    }
    __syncthreads();
    int wexcl = wsum[wid];
    int c = scarry;
    if (idx < N_NODES) rowptr[idx] = c + wexcl + incl - v;
    __syncthreads();
    if (tid == 1023) scarry = c + wexcl + incl;
    __syncthreads();
  }
  if (threadIdx.x == 0) rowptr[N_NODES] = scarry;
}

__global__ void k_fill(const int* __restrict__ esrc, const int* __restrict__ edst,
                       const int* __restrict__ rowptr, int* __restrict__ cursor,
                       int* __restrict__ csr) {
  int i = blockIdx.x * blockDim.x + threadIdx.x;
  if (i < N_EDGES) {
    int d = edst[i];
    int pos = atomicAdd(&cursor[d], 1);
    csr[rowptr[d] + pos] = esrc[i];
  }
}

__global__ void k_counts(const int* __restrict__ batch, int* __restrict__ counts) {
  int v = blockIdx.x * blockDim.x + threadIdx.x;
  if (v < N_NODES) atomicAdd(&counts[batch[v]], 1);
}

__global__ void k_maxlen(const int* __restrict__ counts, float* __restrict__ ml) {
  int m = 0;
  for (int i = threadIdx.x; i < N_GRAPHS; i += 64) m = max(m, counts[i]);
#pragma unroll
  for (int off = 32; off > 0; off >>= 1) m = max(m, __shfl_xor(m, off));
  if (threadIdx.x == 0) *ml = (float)m;
}

// z scatter: z[batch[v]][s] += dinv[s]*dinv[v] per edge; + self-loops
__global__ void k_zscatter(const int* __restrict__ esrc, const int* __restrict__ edst,
                           const int* __restrict__ batch, const float* __restrict__ dinv,
                           float* __restrict__ z) {
  int i = blockIdx.x * blockDim.x + threadIdx.x;
  if (i < N_EDGES) {
    int s = esrc[i], v = edst[i];
    atomicAdd(&z[(size_t)batch[v] * MPAD + s], dinv[s] * dinv[v]);
  } else if (i < N_EDGES + N_NODES) {
    int u = i - N_EDGES;
    atomicAdd(&z[(size_t)batch[u] * MPAD + u], dinv[u] * dinv[u]);
  }
}

__global__ void k_zconv(const float* __restrict__ z, unsigned short* __restrict__ zb) {
  int i = blockIdx.x * blockDim.x + threadIdx.x;  // over 256*MPAD/4
  if (i >= N_GRAPHS * MPAD / 4) return;
  float4 v = ((const float4*)z)[i];
  ushort4 o;
  o.x = f2bf(v.x); o.y = f2bf(v.y); o.z = f2bf(v.z); o.w = f2bf(v.w);
  ((ushort4*)zb)[i] = o;
}

// ---------- GEMM1: h1t[512][MPAD] = relu(A[MPAD,256] @ Wt[512,256]^T + b1)^T ----------
// 128x128 tile, BK=32, 4 waves of 64x64, mfma_f32_16x16x32_bf16.
// Output stored TRANSPOSED (n-major) so the z-GEMM's B operand is in Bt layout.
__global__ __launch_bounds__(256) void k_gemm1(const unsigned short* __restrict__ A,
                                               const unsigned short* __restrict__ Bt,
                                               const float* __restrict__ bias,
                                               unsigned short* __restrict__ Ct) {
  constexpr int KD = 256;
  constexpr int LDR = 40;
  __shared__ unsigned short As[128 * LDR];
  __shared__ unsigned short Bs[128 * LDR];
  const int tid = threadIdx.x;
  const int m0 = blockIdx.x * 128;
  const int n0 = blockIdx.y * 128;
  const int lane = tid & 63;
  const int wid = tid >> 6;
  const int wm = (wid >> 1) * 64;
  const int wn = (wid & 1) * 64;
  const int fr = lane & 15;
  const int fq = lane >> 4;
  const int sr = tid >> 2;
  const int sc = tid & 3;
  const unsigned short* gA = A + (size_t)(m0 + sr) * KD + sc * 8;
  const unsigned short* gB = Bt + (size_t)(n0 + sr) * KD + sc * 8;
  f32x4 acc[4][4] = {};
  for (int k0 = 0; k0 < KD; k0 += 32) {
    bf16x8 a0 = *(const bf16x8*)(gA + k0);
    bf16x8 a1 = *(const bf16x8*)(gA + (size_t)64 * KD + k0);
    bf16x8 b0 = *(const bf16x8*)(gB + k0);
    bf16x8 b1 = *(const bf16x8*)(gB + (size_t)64 * KD + k0);
    __syncthreads();
    *(bf16x8*)&As[sr * LDR + sc * 8] = a0;
    *(bf16x8*)&As[(sr + 64) * LDR + sc * 8] = a1;
    *(bf16x8*)&Bs[sr * LDR + sc * 8] = b0;
    *(bf16x8*)&Bs[(sr + 64) * LDR + sc * 8] = b1;
    __syncthreads();
    bf16x8 af[4], bfr[4];
#pragma unroll
    for (int i = 0; i < 4; ++i)
      af[i] = *(const bf16x8*)&As[(wm + i * 16 + fr) * LDR + fq * 8];
#pragma unroll
    for (int j = 0; j < 4; ++j)
      bfr[j] = *(const bf16x8*)&Bs[(wn + j * 16 + fr) * LDR + fq * 8];
#pragma unroll
    for (int i = 0; i < 4; ++i)
#pragma unroll
      for (int j = 0; j < 4; ++j)
        acc[i][j] = __builtin_amdgcn_mfma_f32_16x16x32_bf16(af[i], bfr[j], acc[i][j], 0, 0, 0);
  }
  float bcol[4];
#pragma unroll
  for (int j = 0; j < 4; ++j) bcol[j] = bias[n0 + wn + j * 16 + fr];
#pragma unroll
  for (int i = 0; i < 4; ++i)
#pragma unroll
    for (int j = 0; j < 4; ++j) {
      ushort4 pk;
      float v0 = fmaxf(acc[i][j][0] + bcol[j], 0.f);
      float v1 = fmaxf(acc[i][j][1] + bcol[j], 0.f);
      float v2 = fmaxf(acc[i][j][2] + bcol[j], 0.f);
      float v3 = fmaxf(acc[i][j][3] + bcol[j], 0.f);
      pk.x = f2bf(v0); pk.y = f2bf(v1); pk.z = f2bf(v2); pk.w = f2bf(v3);
      // transposed: Ct[n][m], jj contiguous in m
      *(ushort4*)(Ct + (size_t)(n0 + wn + j * 16 + fr) * MPAD + (m0 + wm + i * 16 + fq * 4)) = pk;
    }
}

// ---------- z-GEMM: P[bz][256][512] = zb[256, kslice] @ h1t[512, kslice]^T ----------
__global__ __launch_bounds__(256) void k_zgemm(const unsigned short* __restrict__ zb,
                                               const unsigned short* __restrict__ h1t,
                                               float* __restrict__ P) {
  constexpr int LDR = 40;
  __shared__ unsigned short As[128 * LDR];
  __shared__ unsigned short Bs[128 * LDR];
  const int tid = threadIdx.x;
  const int m0 = blockIdx.x * 128;
  const int n0 = blockIdx.y * 128;
  const int kstart = blockIdx.z * KSPAN;
  const int ksteps = min(KSPAN, MPAD - kstart);  // multiple of 32
  const int lane = tid & 63;
  const int wid = tid >> 6;
  const int wm = (wid >> 1) * 64;
  const int wn = (wid & 1) * 64;
  const int fr = lane & 15;
  const int fq = lane >> 4;
  const int sr = tid >> 2;
  const int sc = tid & 3;
  const unsigned short* gA = zb + (size_t)(m0 + sr) * MPAD + kstart + sc * 8;
  const unsigned short* gB = h1t + (size_t)(n0 + sr) * MPAD + kstart + sc * 8;
  f32x4 acc[4][4] = {};
  for (int k0 = 0; k0 < ksteps; k0 += 32) {
    bf16x8 a0 = *(const bf16x8*)(gA + k0);
    bf16x8 a1 = *(const bf16x8*)(gA + (size_t)64 * MPAD + k0);
    bf16x8 b0 = *(const bf16x8*)(gB + k0);
    bf16x8 b1 = *(const bf16x8*)(gB + (size_t)64 * MPAD + k0);
    __syncthreads();
    *(bf16x8*)&As[sr * LDR + sc * 8] = a0;
    *(bf16x8*)&As[(sr + 64) * LDR + sc * 8] = a1;
    *(bf16x8*)&Bs[sr * LDR + sc * 8] = b0;
    *(bf16x8*)&Bs[(sr + 64) * LDR + sc * 8] = b1;
    __syncthreads();
    bf16x8 af[4], bfr[4];
#pragma unroll
    for (int i = 0; i < 4; ++i)
      af[i] = *(const bf16x8*)&As[(wm + i * 16 + fr) * LDR + fq * 8];
#pragma unroll
    for (int j = 0; j < 4; ++j)
      bfr[j] = *(const bf16x8*)&Bs[(wn + j * 16 + fr) * LDR + fq * 8];
#pragma unroll
    for (int i = 0; i < 4; ++i)
#pragma unroll
      for (int j = 0; j < 4; ++j)
        acc[i][j] = __builtin_amdgcn_mfma_f32_16x16x32_bf16(af[i], bfr[j], acc[i][j], 0, 0, 0);
  }
  float* Pp = P + (size_t)blockIdx.z * (N_GRAPHS * 512);
#pragma unroll
  for (int i = 0; i < 4; ++i)
#pragma unroll
    for (int j = 0; j < 4; ++j) {
      float* cp = Pp + (size_t)(m0 + wm + i * 16 + fq * 4) * 512 + (n0 + wn + j * 16 + fr);
#pragma unroll
      for (int jj = 0; jj < 4; ++jj) cp[(size_t)jj * 512] = acc[i][j][jj];
    }
}

__global__ void k_sreduce(const float* __restrict__ P, float* __restrict__ S) {
  int i = blockIdx.x * blockDim.x + threadIdx.x;
  if (i >= N_GRAPHS * 512) return;
  float s = 0.f;
  for (int b = 0; b < NKS; ++b) s += P[(size_t)b * (N_GRAPHS * 512) + i];
  S[i] = s;
}

// ---------- final: out = tanh((S @ W2 + counts*b2) / ml), all f32 ----------
__global__ __launch_bounds__(256) void k_final(const float* __restrict__ S,
                                               const float* __restrict__ W2,
                                               const float* __restrict__ b2,
                                               const int* __restrict__ counts,
                                               const float* __restrict__ mlp,
                                               float* __restrict__ out) {
  __shared__ float sS[8][512];
  const int g0 = blockIdx.x * 8;
  const int tid = threadIdx.x;
  for (int i = tid; i < 8 * 512; i += 256)
    sS[i >> 9][i & 511] = S[(size_t)(g0 + (i >> 9)) * 512 + (i & 511)];
  __syncthreads();
  const int n = tid * 2;
  float a0[8] = {}, a1[8] = {};
  for (int k = 0; k < 512; ++k) {
    float2 w = *(const float2*)&W2[(size_t)k * 512 + n];
#pragma unroll
    for (int r = 0; r < 8; ++r) {
      float s = sS[r][k];
      a0[r] += s * w.x;
      a1[r] += s * w.y;
    }
  }
  const float inv_ml = 1.f / mlp[0];
  const float2 bb = *(const float2*)&b2[n];
#pragma unroll
  for (int r = 0; r < 8; ++r) {
    const int g = g0 + r;
    const float c = (float)counts[g];
    out[(size_t)g * 512 + n] = tanhf((a0[r] + c * bb.x) * inv_ml);
    out[(size_t)g * 512 + n + 1] = tanhf((a1[r] + c * bb.y) * inv_ml);
  }
}

// ---------- layer-1 aggregation (unchanged structure, D=256) ----------
#define MAXE 256
__global__ __launch_bounds__(256) void k_agg256(const unsigned short* __restrict__ xw,
                                                const float* __restrict__ dinv,
                                                const int* __restrict__ rowptr,
                                                const int* __restrict__ csr,
                                                unsigned short* __restrict__ hout) {
  constexpr int D = 256, VEC = 4, SP = 5;
  const int v = blockIdx.x;
  const int tid = threadIdx.x;
  const int lane = tid & 63, wid = tid >> 6;
  __shared__ int s_src[MAXE];
  __shared__ float s_w[MAXE];
  __shared__ float s_red[4][64 * SP];
  const int e0 = rowptr[v], e1 = rowptr[v + 1];
  float acc[VEC] = {};
  const unsigned short* rowbase = xw + lane * VEC;
  for (int eb = e0; eb < e1; eb += MAXE) {
    const int cnt = min(e1 - eb, MAXE);
    __syncthreads();
    if (tid < cnt) {
      int s = csr[eb + tid];
      s_src[tid] = s;
      s_w[tid] = dinv[s];
    }
    __syncthreads();
    int i = wid;
    for (; i + 4 < cnt; i += 8) {
      const int s0 = s_src[i], s1 = s_src[i + 4];
      const float w0 = s_w[i], w1 = s_w[i + 4];
      bf16x4 t0 = *(const bf16x4*)(rowbase + (size_t)s0 * D);
      bf16x4 t1 = *(const bf16x4*)(rowbase + (size_t)s1 * D);
#pragma unroll
      for (int j = 0; j < VEC; ++j) acc[j] += w0 * bf2f((unsigned short)t0[j]);
#pragma unroll
      for (int j = 0; j < VEC; ++j) acc[j] += w1 * bf2f((unsigned short)t1[j]);
    }
    if (i < cnt) {
      const int s0 = s_src[i];
      const float w0 = s_w[i];
      bf16x4 t0 = *(const bf16x4*)(rowbase + (size_t)s0 * D);
#pragma unroll
      for (int j = 0; j < VEC; ++j) acc[j] += w0 * bf2f((unsigned short)t0[j]);
    }
  }
#pragma unroll
  for (int j = 0; j < VEC; ++j) s_red[wid][lane * SP + j] = acc[j];
  __syncthreads();
  const float dv = dinv[v];
  const int c = tid;
  const int co = (c / VEC) * SP + (c % VEC);
  float o = s_red[0][co] + s_red[1][co] + s_red[2][co] + s_red[3][co];
  float self = bf2f(xw[(size_t)v * D + c]);
  hout[(size_t)v * D + c] = f2bf(dv * (o + dv * self));
}

// ---------- launch ----------

extern "C" void kernel_launch(void* const* d_in, const int* in_sizes, int n_in,
                              void* d_out, int out_size, void* d_ws, size_t ws_size,
                              hipStream_t stream) {
  (void)in_sizes; (void)n_in; (void)out_size; (void)ws_size;
  const float* x = (const float*)d_in[0];
  const float* W1 = (const float*)d_in[1];
  const float* b1 = (const float*)d_in[2];
  const float* W2 = (const float*)d_in[3];
  const float* b2 = (const float*)d_in[4];
  const int* ei = (const int*)d_in[5];
  const int* batch = (const int*)d_in[6];
  const int* esrc = ei;
  const int* edst = ei + N_EDGES;
  float* out = (float*)d_out;

  char* p = (char*)d_ws;
  auto alloc = [&](size_t bytes) {
    char* r = p;
    p += (bytes + 255) & ~(size_t)255;
    return r;
  };
  // region0: xb (25.6MB) + ag1 (25.6MB) early; reused as z (51.25MB) after gemm1
  char* region0 = alloc((size_t)N_GRAPHS * MPAD * 4);  // 51.25 MB
  unsigned short* xb = (unsigned short*)region0;                         // [50000][256] bf16
  unsigned short* ag1 = (unsigned short*)(region0 + (size_t)N_NODES * D_IN * 2);  // [MPAD][256] bf16
  float* z = (float*)region0;                                            // [256][MPAD] f32
  unsigned short* h1t = (unsigned short*)alloc((size_t)MPAD * D_HID * 2);  // [512][MPAD] bf16 (transposed)
  unsigned short* zb = (unsigned short*)alloc((size_t)N_GRAPHS * MPAD * 2); // [256][MPAD] bf16
  unsigned short* wt = (unsigned short*)alloc((size_t)512 * 256 * 2);
  float* P = (float*)alloc((size_t)NKS * N_GRAPHS * 512 * 4);            // 16.8 MB partials
  float* S = (float*)alloc((size_t)N_GRAPHS * 512 * 4);
  int* deg = (int*)alloc((size_t)N_NODES * 4);
  int* rowptr = (int*)alloc((size_t)(N_NODES + 4) * 4);
  int* cursor = (int*)alloc((size_t)N_NODES * 4);
  int* csr = (int*)alloc((size_t)N_EDGES * 4);
  int* counts = (int*)alloc(256 * 4);
  float* ml = (float*)alloc(256);
  float* dinv = (float*)alloc((size_t)N_NODES * 4);

  hipMemsetAsync(deg, 0, (size_t)N_NODES * 4, stream);
  hipMemsetAsync(cursor, 0, (size_t)N_NODES * 4, stream);
  hipMemsetAsync(counts, 0, 256 * 4, stream);
  // zero ag1 pad rows (keep gemm1 pad outputs finite; zb pad cols are zero anyway)
  hipMemsetAsync((char*)ag1 + (size_t)N_NODES * D_IN * 2, 0,
                 (size_t)(MPAD - N_NODES) * D_IN * 2, stream);

  k_deg<<<(N_EDGES + 255) / 256, 256, 0, stream>>>(edst, deg);
  k_dinv<<<(N_NODES + 255) / 256, 256, 0, stream>>>(deg, dinv);
  k_scan<<<1, 1024, 0, stream>>>(deg, rowptr);
  k_fill<<<(N_EDGES + 255) / 256, 256, 0, stream>>>(esrc, edst, rowptr, cursor, csr);
  k_counts<<<(N_NODES + 255) / 256, 256, 0, stream>>>(batch, counts);
  k_maxlen<<<1, 64, 0, stream>>>(counts, ml);

  // layer 1: aggregate X (256-d), then GEMM with fused bias+relu, transposed output
  k_convert_x<<<(N_NODES * D_IN / 4 + 255) / 256, 256, 0, stream>>>(x, xb);
  k_agg256<<<N_NODES, 256, 0, stream>>>(xb, dinv, rowptr, csr, ag1);
  k_wt<<<(256 * 512 + 255) / 256, 256, 0, stream>>>(W1, wt);
  k_gemm1<<<dim3(MPAD / 128, 4), 256, 0, stream>>>(ag1, wt, b1, h1t);

  // layer 2 (algebraic): z scatter -> z-GEMM -> reduce -> small f32 GEMM + tanh
  // (xb/ag1 are dead now; z aliases their region, stream-ordered after gemm1)
  hipMemsetAsync(z, 0, (size_t)N_GRAPHS * MPAD * 4, stream);
  k_zscatter<<<(N_EDGES + N_NODES + 255) / 256, 256, 0, stream>>>(esrc, edst, batch, dinv, z);
  k_zconv<<<(N_GRAPHS * MPAD / 4 + 255) / 256, 256, 0, stream>>>(z, zb);
  k_zgemm<<<dim3(2, 4, NKS), 256, 0, stream>>>(zb, h1t, P);
  k_sreduce<<<(N_GRAPHS * 512 + 255) / 256, 256, 0, stream>>>(P, S);
  k_final<<<N_GRAPHS / 8, 256, 0, stream>>>(S, W2, b2, counts, ml, out);
}